// Round 1
// baseline (203.285 us; speedup 1.0000x reference)
//
#include <hip/hip_runtime.h>
#include <math.h>

#define NOISE 1e-12f

__device__ __forceinline__ float2 cmul(float2 a, float2 b) {
    return make_float2(a.x*b.x - a.y*b.y, a.x*b.y + a.y*b.x);
}
// conj(a)*b
__device__ __forceinline__ float2 cconjmul(float2 a, float2 b) {
    return make_float2(a.x*b.x + a.y*b.y, a.x*b.y - a.y*b.x);
}
// a*conj(b)
__device__ __forceinline__ float2 cmulconj(float2 a, float2 b) {
    return make_float2(a.x*b.x + a.y*b.y, a.y*b.x - a.x*b.y);
}
__device__ __forceinline__ float2 cadd(float2 a, float2 b){ return make_float2(a.x+b.x, a.y+b.y); }
__device__ __forceinline__ float2 csub(float2 a, float2 b){ return make_float2(a.x-b.x, a.y-b.y); }
__device__ __forceinline__ float2 cscale(float s, float2 a){ return make_float2(s*a.x, s*a.y); }

// one wave per batch element; 4 waves/block; 4 iterations -> 16 b per block
__global__ __launch_bounds__(256) void rate_kernel(
    const float* __restrict__ t1,
    const float* __restrict__ G1r, const float* __restrict__ G1i,
    const float* __restrict__ G2r, const float* __restrict__ G2i,
    const float* __restrict__ Ur,  const float* __restrict__ Ui,
    float* __restrict__ partial)
{
    __shared__ float2 ent[4][16];
    __shared__ float wsum[4];
    const int wave = threadIdx.x >> 6;
    const int lane = threadIdx.x & 63;
    const int t  = lane & 7;     // output column of phi
    const int k0 = lane >> 3;    // k-strip (k = 8j + k0), reused as entry-octet id
    const int e8 = k0;
    const int nn = (e8 >> 1) & 1;
    const int rr = e8 & 1;

    float acc = 0.0f;

    for (int it = 0; it < 4; ++it) {
        const long b = (long)blockIdx.x * 16 + (long)wave * 4 + it;
        const float* t1b  = t1  + b * 264;
        const float* g1rb = G1r + b * 200;
        const float* g1ib = G1i + b * 200;
        const float* g2rb = G2r + b * 200;
        const float* g2ib = G2i + b * 200;
        const float* urb  = Ur  + b * 800;
        const float* uib  = Ui  + b * 800;

        // ---- phi_g[n][t] partial sums over this lane's k-strip ----
        float p1r0=0.f,p1i0=0.f,p1r1=0.f,p1i1=0.f;
        float p2r0=0.f,p2i0=0.f,p2r1=0.f,p2i1=0.f;
        for (int j = 0; j < 13; ++j) {
            int k = 8*j + k0;
            if (k < 100) {
                float thr = t1b[k], thi = t1b[100+k];
                float ur = urb[k*8 + t], ui = uib[k*8 + t];   // flat = 64j+lane: coalesced
                {
                    float gr = g1rb[k], gi = g1ib[k];
                    float vr = gr*thr - gi*thi, vi = gr*thi + gi*thr;
                    p1r0 += vr*ur - vi*ui; p1i0 += vr*ui + vi*ur;
                }
                {
                    float gr = g1rb[100+k], gi = g1ib[100+k];
                    float vr = gr*thr - gi*thi, vi = gr*thi + gi*thr;
                    p1r1 += vr*ur - vi*ui; p1i1 += vr*ui + vi*ur;
                }
                {
                    float gr = g2rb[k], gi = g2ib[k];
                    float vr = gr*thr - gi*thi, vi = gr*thi + gi*thr;
                    p2r0 += vr*ur - vi*ui; p2i0 += vr*ui + vi*ur;
                }
                {
                    float gr = g2rb[100+k], gi = g2ib[100+k];
                    float vr = gr*thr - gi*thi, vi = gr*thi + gi*thr;
                    p2r1 += vr*ur - vi*ui; p2i1 += vr*ui + vi*ur;
                }
            }
        }
        // reduce over the 8 k-strips (lanes differing in bits 3..5)
        #pragma unroll
        for (int s = 8; s < 64; s <<= 1) {
            p1r0 += __shfl_xor(p1r0, s); p1i0 += __shfl_xor(p1i0, s);
            p1r1 += __shfl_xor(p1r1, s); p1i1 += __shfl_xor(p1i1, s);
            p2r0 += __shfl_xor(p2r0, s); p2i0 += __shfl_xor(p2i0, s);
            p2r1 += __shfl_xor(p2r1, s); p2i1 += __shfl_xor(p2i1, s);
        }
        // now every lane holds full phi1[n][t], phi2[n][t] for t = lane&7

        // ---- F norms: scale_h = sqrt(2 / sum|F_h|^2) ----
        float s1, s2;
        {
            int idx = lane & 15;
            int sel = (lane >> 4) & 1;
            float fr = t1b[200 + sel*32 + idx];
            float fi = t1b[200 + sel*32 + 16 + idx];
            float m = fr*fr + fi*fi;
            #pragma unroll
            for (int s = 1; s < 16; s <<= 1) m += __shfl_xor(m, s);
            float other = __shfl_xor(m, 16);
            float nrm1 = sel ? other : m;
            float nrm2 = sel ? m : other;
            s1 = sqrtf(2.0f / nrm1);
            s2 = sqrtf(2.0f / nrm2);
        }

        // ---- A/C entries: e = mat*4 + n*2 + r ----
        // mats: 0 = A1 = phi1*F1 (s1), 1 = C1 = phi1*F2 (s2),
        //       2 = A2 = phi2*F2 (s2), 3 = C2 = phi2*F1 (s1)
        // lane computes per-t partial for entries e8 (E0, phi1) and e8+8 (E1, phi2)
        {
            int jf = t*2 + rr;
            float2 f1 = make_float2(t1b[200 + jf], t1b[216 + jf]);
            float2 f2 = make_float2(t1b[232 + jf], t1b[248 + jf]);
            float2 phi1n = nn ? make_float2(p1r1,p1i1) : make_float2(p1r0,p1i0);
            float2 phi2n = nn ? make_float2(p2r1,p2i1) : make_float2(p2r0,p2i0);
            bool loA = (e8 < 4);
            float2 E0 = cmul(phi1n, loA ? f1 : f2);
            float2 E1 = cmul(phi2n, loA ? f2 : f1);
            #pragma unroll
            for (int s = 1; s < 8; s <<= 1) {
                E0.x += __shfl_xor(E0.x, s); E0.y += __shfl_xor(E0.y, s);
                E1.x += __shfl_xor(E1.x, s); E1.y += __shfl_xor(E1.y, s);
            }
            if (t == 0) {
                ent[wave][e8]     = cscale(loA ? s1 : s2, E0);
                ent[wave][e8 + 8] = cscale(loA ? s2 : s1, E1);
            }
        }
        __builtin_amdgcn_wave_barrier();

        // ---- 2x2 complex rate: lane 0 -> R1, lane 1 -> R2 ----
        float negR = 0.0f;
        if (lane < 2) {
            const float2* e = &ent[wave][lane * 8];
            float2 A00=e[0], A01=e[1], A10=e[2], A11=e[3];
            float2 C00=e[4], C01=e[5], C10=e[6], C11=e[7];
            // Mu = C C^H + NOISE (added to real part of all entries)
            float mu00 = C00.x*C00.x + C00.y*C00.y + C01.x*C01.x + C01.y*C01.y + NOISE;
            float mu11 = C10.x*C10.x + C10.y*C10.y + C11.x*C11.x + C11.y*C11.y + NOISE;
            float2 mu01 = cadd(cmulconj(C00, C10), cmulconj(C01, C11));
            mu01.x += NOISE;  // mu10 = conj(mu01) stays exact
            float det = mu00*mu11 - (mu01.x*mu01.x + mu01.y*mu01.y);
            float inv = 1.0f / det;
            // X = Mu^-1 * A
            float2 mu01c = make_float2(mu01.x, -mu01.y);
            float2 X00 = cscale(inv, csub(cscale(mu11, A00), cmul(mu01,  A10)));
            float2 X01 = cscale(inv, csub(cscale(mu11, A01), cmul(mu01,  A11)));
            float2 X10 = cscale(inv, csub(cscale(mu00, A10), cmul(mu01c, A00)));
            float2 X11 = cscale(inv, csub(cscale(mu00, A11), cmul(mu01c, A01)));
            // inner[r][s] = sum_n conj(A[n][r]) X[n][s]
            float2 I00 = cadd(cconjmul(A00, X00), cconjmul(A10, X10));
            float2 I01 = cadd(cconjmul(A00, X01), cconjmul(A10, X11));
            float2 I10 = cadd(cconjmul(A01, X00), cconjmul(A11, X10));
            float2 I11 = cadd(cconjmul(A01, X01), cconjmul(A11, X11));
            I00.x += 1.0f; I01.x += 1.0f; I10.x += 1.0f; I11.x += 1.0f;
            float2 dT = csub(cmul(I00, I11), cmul(I01, I10));
            float rate = 0.5f * logf(dT.x*dT.x + dT.y*dT.y);  // Re(log z) = ln|z|
            negR = -rate;
        }
        float o = __shfl(negR, 1);
        if (lane == 0) acc += fmaxf(negR, o);
    }

    if (lane == 0) wsum[wave] = acc;
    __syncthreads();
    if (threadIdx.x == 0)
        partial[blockIdx.x] = (wsum[0] + wsum[1]) + (wsum[2] + wsum[3]);
}

__global__ __launch_bounds__(256) void reduce_kernel(
    const float* __restrict__ partial, int n, float invB, float* __restrict__ out)
{
    __shared__ float sd[256];
    float s = 0.0f;
    for (int i = threadIdx.x; i < n; i += 256) s += partial[i];
    sd[threadIdx.x] = s;
    __syncthreads();
    for (int o = 128; o > 0; o >>= 1) {
        if ((int)threadIdx.x < o) sd[threadIdx.x] += sd[threadIdx.x + o];
        __syncthreads();
    }
    if (threadIdx.x == 0) out[0] = sd[0] * invB;
}

extern "C" void kernel_launch(void* const* d_in, const int* in_sizes, int n_in,
                              void* d_out, int out_size, void* d_ws, size_t ws_size,
                              hipStream_t stream) {
    const float* t1  = (const float*)d_in[0];
    const float* G1r = (const float*)d_in[1];
    const float* G1i = (const float*)d_in[2];
    const float* G2r = (const float*)d_in[3];
    const float* G2i = (const float*)d_in[4];
    const float* Ur  = (const float*)d_in[5];
    const float* Ui  = (const float*)d_in[6];

    const int B = in_sizes[0] / 264;        // 65536
    const int nblocks = B / 16;             // 16 batch elements per block
    float* partial = (float*)d_ws;          // nblocks floats

    rate_kernel<<<nblocks, 256, 0, stream>>>(t1, G1r, G1i, G2r, G2i, Ur, Ui, partial);
    reduce_kernel<<<1, 256, 0, stream>>>(partial, nblocks, 1.0f / (float)B, (float*)d_out);
}